// Round 1
// baseline (4329.025 us; speedup 1.0000x reference)
//
#include <hip/hip_runtime.h>

#define SEQ_LEN 256
#define SPIKE_STEPS 7
#define T_TOTAL (SEQ_LEN * SPIKE_STEPS)
#define BATCH 128
#define IN_DIM 96
#define HIDDEN 512
#define OUT_DIM 2

// Weight buffers carry an extra all-zero row (index 512) used to pad the
// active list to a multiple of 16 — enables a fixed-trip-count, software-
// pipelined inner loop with two 16-load groups in flight.
#define WROWS (HIDDEN + 1)

// d_ws layout: W0T [96*512] | W1T [513*512] | W2T [513*512] | ctr[128] | zbuf[B][T][8] u64
#define W0T_OFF 0
#define W1T_OFF (IN_DIM * HIDDEN)
#define W2T_OFF (W1T_OFF + WROWS * HIDDEN)
#define CTR_BYTE_OFF ((size_t)(W2T_OFF + WROWS * HIDDEN) * sizeof(float))   // 1KB-aligned
#define ZBUF_BYTE_OFF (CTR_BYTE_OFF + 1024)

__global__ void transpose_kernel(const float* __restrict__ in, float* __restrict__ out,
                                 int rows, int cols) {
    int idx = blockIdx.x * blockDim.x + threadIdx.x;
    if (idx < rows * cols) {
        int r = idx / cols, c = idx - r * cols;
        out[c * rows + r] = in[idx];
    }
}

// Sum of active weight rows, software-pipelined: 16-row groups, next group's
// loads issued before current group's adds => compiler emits vmcnt(16) not
// vmcnt(0); ~32 outstanding loads per thread. npad multiple of 16 via zero-row
// padding => no remainder loop. Add order = ascending act + trailing zeros =>
// bit-identical to the simple in-order sum.
__device__ __forceinline__ float row_sum_pipelined(const float* __restrict__ W,
                                                   const int* __restrict__ act,
                                                   int npad, int tid) {
    float cur = 0.f;
    if (npad > 0) {
        float buf[16];
        #pragma unroll
        for (int k = 0; k < 16; ++k) buf[k] = W[act[k] * HIDDEN + tid];
        for (int n = 16; n < npad; n += 16) {
            float nxt[16];
            #pragma unroll
            for (int k = 0; k < 16; ++k) nxt[k] = W[act[n + k] * HIDDEN + tid];
            #pragma unroll
            for (int k = 0; k < 16; ++k) cur = __fadd_rn(cur, buf[k]);
            #pragma unroll
            for (int k = 0; k < 16; ++k) buf[k] = nxt[k];
        }
        #pragma unroll
        for (int k = 0; k < 16; ++k) cur = __fadd_rn(cur, buf[k]);
    }
    return cur;
}

// Two-stage pipeline: even blocks = producer (layer0+layer1),
// odd = consumer (layer2+output); per-step mask handoff through L2 with
// relaxed agent-scope atomics.
__launch_bounds__(512, 1)
__global__ void snn_pipe_kernel(const float* __restrict__ x,     // [256,128,96]
                                const float* __restrict__ Wout,  // [2,512]
                                const float* __restrict__ betas, // [3]
                                const float* __restrict__ thrs,  // [3]
                                const float* __restrict__ W0T,   // [96,512]
                                const float* __restrict__ W1T,   // [513,512]
                                const float* __restrict__ W2T,   // [513,512]
                                unsigned long long* __restrict__ zbuf,
                                int* __restrict__ ctr,
                                float* __restrict__ out)         // [256,128,2]
{
    const int b    = blockIdx.x >> 1;
    const int role = blockIdx.x & 1;
    const int tid  = threadIdx.x;
    const int lane = tid & 63;
    const int wid  = tid >> 6;

    __shared__ float xs[IN_DIM];
    __shared__ unsigned long long zm[8];
    __shared__ int act[HIDDEN];
    __shared__ float red[16];

    if (role == 0) {
        // ---------------- producer: layer0 + layer1 ----------------
        const float beta0 = betas[0], beta1 = betas[1];
        const float thr0  = thrs[0],  thr1  = thrs[1];
        float mem0 = 0.f, mem1 = 0.f;
        unsigned long long* zb = zbuf + (size_t)b * T_TOTAL * 8;

        for (int i = 0; i < SEQ_LEN; ++i) {
            if (tid < IN_DIM) xs[tid] = x[(i * BATCH + b) * IN_DIM + tid];
            __syncthreads();

            float cur0 = 0.f;
            #pragma unroll 8
            for (int k = 0; k < IN_DIM; ++k)
                cur0 = __fmaf_rn(xs[k], W0T[k * HIDDEN + tid], cur0);

            for (int s = 0; s < SPIKE_STEPS; ++s) {
                const int t = i * SPIKE_STEPS + s;

                // layer 0 LIF
                bool reset0 = (mem0 - thr0) > 0.f;
                mem0 = reset0 ? 0.f : __fadd_rn(__fmul_rn(beta0, mem0), cur0);
                bool z0 = (mem0 - thr0) > 0.f;
                unsigned long long bal = __ballot(z0);
                if (lane == 0) zm[wid] = bal;
                __syncthreads();

                int nact, npad;
                {
                    int pre = 0, total = 0;
                    #pragma unroll
                    for (int q = 0; q < 8; ++q) {
                        int p = __popcll(zm[q]);
                        total += p;
                        if (q < wid) pre += p;
                    }
                    int rank = pre + __popcll(zm[wid] & ((1ull << lane) - 1ull));
                    if (z0) act[rank] = tid;
                    nact = total;
                    npad = (nact + 15) & ~15;
                    if (tid < npad - nact) act[nact + tid] = HIDDEN;  // zero-row pads
                }
                __syncthreads();

                float cur1 = row_sum_pipelined(W1T, act, npad, tid);

                // layer 1 LIF
                bool reset1 = (mem1 - thr1) > 0.f;
                mem1 = reset1 ? 0.f : __fadd_rn(__fmul_rn(beta1, mem1), cur1);
                bool z1 = (mem1 - thr1) > 0.f;

                unsigned long long bal1 = __ballot(z1);
                if (lane == 0)
                    __hip_atomic_store(&zb[(size_t)t * 8 + wid], bal1,
                                       __ATOMIC_RELAXED, __HIP_MEMORY_SCOPE_AGENT);
                __syncthreads();   // vmcnt(0) drain before barrier => masks visible
                if (tid == 0)
                    __hip_atomic_store(&ctr[b], t + 1,
                                       __ATOMIC_RELAXED, __HIP_MEMORY_SCOPE_AGENT);
            }
        }
    } else {
        // ---------------- consumer: layer2 + output ----------------
        const float beta2 = betas[2];
        const float thr2  = thrs[2];
        const float wo0 = Wout[tid];
        const float wo1 = Wout[HIDDEN + tid];
        float mem2 = 0.f;
        // Deferred output reduction: per-thread all-time integrator
        // contribution a = Σ_t (z2 ? wo : 0). mem_out after step s is
        // reduce(a_after_s), and the per-seq-step decoded mean is
        //   (1/7) Σ_s reduce(a_after_s) = (1/7) reduce(Σ_s a_after_s).
        // So we keep w += a per spike step and reduce w ONCE per seq step,
        // removing 1 barrier + 12 shfls + tid0 serial chain from every
        // spike step. Spike decisions (mem2) are untouched => only the
        // linear post-spike sum is reassociated (ulp-level).
        float a0 = 0.f, a1 = 0.f;
        const unsigned long long* zb = zbuf + (size_t)b * T_TOTAL * 8;

        for (int i = 0; i < SEQ_LEN; ++i) {
            float w0 = 0.f, w1 = 0.f;

            for (int s = 0; s < SPIKE_STEPS; ++s) {
                const int t = i * SPIKE_STEPS + s;

                if (tid == 0) {
                    while (__hip_atomic_load(&ctr[b], __ATOMIC_RELAXED,
                                             __HIP_MEMORY_SCOPE_AGENT) < t + 1)
                        __builtin_amdgcn_s_sleep(1);
                }
                __syncthreads();

                if (tid < 8)
                    zm[tid] = __hip_atomic_load(&zb[(size_t)t * 8 + tid],
                                                __ATOMIC_RELAXED, __HIP_MEMORY_SCOPE_AGENT);
                __syncthreads();

                bool z1 = (zm[wid] >> lane) & 1ull;
                int nact, npad;
                {
                    int pre = 0, total = 0;
                    #pragma unroll
                    for (int q = 0; q < 8; ++q) {
                        int p = __popcll(zm[q]);
                        total += p;
                        if (q < wid) pre += p;
                    }
                    int rank = pre + __popcll(zm[wid] & ((1ull << lane) - 1ull));
                    if (z1) act[rank] = tid;
                    nact = total;
                    npad = (nact + 15) & ~15;
                    if (tid < npad - nact) act[nact + tid] = HIDDEN;  // zero-row pads
                }
                __syncthreads();

                float cur2 = row_sum_pipelined(W2T, act, npad, tid);

                // layer 2 LIF
                bool reset2 = (mem2 - thr2) > 0.f;
                mem2 = reset2 ? 0.f : __fadd_rn(__fmul_rn(beta2, mem2), cur2);
                bool z2 = (mem2 - thr2) > 0.f;

                // output integrator, deferred: 4 VALU ops, no reduction here
                a0 += z2 ? wo0 : 0.f;
                a1 += z2 ? wo1 : 0.f;
                w0 += a0;
                w1 += a1;
            }

            // one cross-thread reduction per seq step
            float c0 = w0, c1 = w1;
            #pragma unroll
            for (int off = 32; off > 0; off >>= 1) {
                c0 += __shfl_down(c0, off);
                c1 += __shfl_down(c1, off);
            }
            if (lane == 0) { red[wid * 2] = c0; red[wid * 2 + 1] = c1; }
            __syncthreads();
            if (tid == 0) {
                float r0 = 0.f, r1 = 0.f;
                #pragma unroll
                for (int q = 0; q < 8; ++q) { r0 += red[q * 2]; r1 += red[q * 2 + 1]; }
                out[(i * BATCH + b) * OUT_DIM + 0] = r0 / 7.0f;
                out[(i * BATCH + b) * OUT_DIM + 1] = r1 / 7.0f;
            }
            // no extra barrier needed: next write to red is 7 spike steps
            // (≥21 barriers) away, and tid0's read precedes its next barrier.
        }
    }
}

extern "C" void kernel_launch(void* const* d_in, const int* in_sizes, int n_in,
                              void* d_out, int out_size, void* d_ws, size_t ws_size,
                              hipStream_t stream) {
    const float* x     = (const float*)d_in[0];
    const float* W0    = (const float*)d_in[1];
    const float* W1    = (const float*)d_in[2];
    const float* W2    = (const float*)d_in[3];
    const float* Wout  = (const float*)d_in[4];
    const float* betas = (const float*)d_in[5];
    const float* thrs  = (const float*)d_in[6];
    float* out = (float*)d_out;

    float* ws  = (float*)d_ws;
    float* W0T = ws + W0T_OFF;
    float* W1T = ws + W1T_OFF;
    float* W2T = ws + W2T_OFF;
    int* ctr = (int*)((char*)d_ws + CTR_BYTE_OFF);
    unsigned long long* zbuf = (unsigned long long*)((char*)d_ws + ZBUF_BYTE_OFF);

    {
        int n = HIDDEN * IN_DIM;
        transpose_kernel<<<(n + 255) / 256, 256, 0, stream>>>(W0, W0T, HIDDEN, IN_DIM);
    }
    {
        int n = HIDDEN * HIDDEN;
        transpose_kernel<<<(n + 255) / 256, 256, 0, stream>>>(W1, W1T, HIDDEN, HIDDEN);
        transpose_kernel<<<(n + 255) / 256, 256, 0, stream>>>(W2, W2T, HIDDEN, HIDDEN);
    }

    // zero the pad row (index 512) of W1T/W2T, and the progress counters
    hipMemsetAsync(W1T + (size_t)HIDDEN * HIDDEN, 0, HIDDEN * sizeof(float), stream);
    hipMemsetAsync(W2T + (size_t)HIDDEN * HIDDEN, 0, HIDDEN * sizeof(float), stream);
    hipMemsetAsync((char*)d_ws + CTR_BYTE_OFF, 0, 1024, stream);

    snn_pipe_kernel<<<2 * BATCH, HIDDEN, 0, stream>>>(
        x, Wout, betas, thrs, W0T, W1T, W2T, zbuf, ctr, out);
}

// Round 3
// 3729.431 us; speedup vs baseline: 1.1608x; 1.1608x over previous
//
#include <hip/hip_runtime.h>

#define SEQ_LEN 256
#define SPIKE_STEPS 7
#define T_TOTAL (SEQ_LEN * SPIKE_STEPS)
#define BATCH 128
#define IN_DIM 96
#define HIDDEN 512
#define OUT_DIM 2

// Weight buffers carry an extra all-zero row (index 512) used to pad the
// active list to a multiple of 16.
#define WROWS (HIDDEN + 1)

// d_ws layout (f32 weights): W0T [96*512] | W1T [513*512] | W2T [513*512] | ctr | zbuf
#define W0T_OFF 0
#define W1T_OFF (IN_DIM * HIDDEN)
#define W2T_OFF (W1T_OFF + WROWS * HIDDEN)
#define CTR_BYTE_OFF ((size_t)(W2T_OFF + WROWS * HIDDEN) * sizeof(float))
#define ZBUF_BYTE_OFF (CTR_BYTE_OFF + 1024)

__global__ void transpose_kernel(const float* __restrict__ in, float* __restrict__ out,
                                 int rows, int cols) {
    int idx = blockIdx.x * blockDim.x + threadIdx.x;
    if (idx < rows * cols) {
        int r = idx / cols, c = idx - r * cols;
        out[c * rows + r] = in[idx];
    }
}

// Union-batched 7-step row sum: each union row is loaded ONCE from L2 and
// applied to the 7 per-step accumulators via fma with a {0,1} float mask
// read broadcast from LDS (fm[row][8], 32B, 2x ds_read_b128).
// Active contributions: fma(1.0,w,acc) == acc+w (single rounding, identical
// to fadd). Inactive: fma(0.0,w,acc) == acc + (+/-0) == acc exactly (acc is
// never -0: it starts +0 and +0 + +/-0 = +0 in RN). => bit-identical to the
// per-step ordered active-row sums of the R1 kernel.
// 16-row groups, next group's global loads issued before current group's
// fmas => deep vmcnt pipelining, no remainder loop (zero-row pads).
__device__ __forceinline__ void row_sum7(const float* __restrict__ W,
                                         const int* __restrict__ act,
                                         const float (* __restrict__ fm)[8],
                                         int npad, int tid,
                                         float acc[SPIKE_STEPS]) {
    if (npad <= 0) return;
    const float* Wt = W + tid;
    float wbuf[16];
    #pragma unroll
    for (int k = 0; k < 16; ++k) wbuf[k] = Wt[act[k] * HIDDEN];
    int base = 0;
    for (int n = 16; n < npad; n += 16) {
        float wnxt[16];
        #pragma unroll
        for (int k = 0; k < 16; ++k) wnxt[k] = Wt[act[n + k] * HIDDEN];
        #pragma unroll
        for (int k = 0; k < 16; ++k) {
            const float4* fv = reinterpret_cast<const float4*>(fm[base + k]);
            float4 fa = fv[0];
            float4 fb = fv[1];
            acc[0] = __fmaf_rn(fa.x, wbuf[k], acc[0]);
            acc[1] = __fmaf_rn(fa.y, wbuf[k], acc[1]);
            acc[2] = __fmaf_rn(fa.z, wbuf[k], acc[2]);
            acc[3] = __fmaf_rn(fa.w, wbuf[k], acc[3]);
            acc[4] = __fmaf_rn(fb.x, wbuf[k], acc[4]);
            acc[5] = __fmaf_rn(fb.y, wbuf[k], acc[5]);
            acc[6] = __fmaf_rn(fb.z, wbuf[k], acc[6]);
        }
        #pragma unroll
        for (int k = 0; k < 16; ++k) wbuf[k] = wnxt[k];
        base = n;
    }
    #pragma unroll
    for (int k = 0; k < 16; ++k) {
        const float4* fv = reinterpret_cast<const float4*>(fm[base + k]);
        float4 fa = fv[0];
        float4 fb = fv[1];
        acc[0] = __fmaf_rn(fa.x, wbuf[k], acc[0]);
        acc[1] = __fmaf_rn(fa.y, wbuf[k], acc[1]);
        acc[2] = __fmaf_rn(fa.z, wbuf[k], acc[2]);
        acc[3] = __fmaf_rn(fa.w, wbuf[k], acc[3]);
        acc[4] = __fmaf_rn(fb.x, wbuf[k], acc[4]);
        acc[5] = __fmaf_rn(fb.y, wbuf[k], acc[5]);
        acc[6] = __fmaf_rn(fb.z, wbuf[k], acc[6]);
    }
}

// Build the union active list + per-row 7-bit step masks (as floats).
// m7 = this thread's 7 firing bits. Rank = compact ascending index over the
// union mask => same ascending add order as the per-step lists.
__device__ __forceinline__ int build_union(const unsigned long long (*zm7)[8],
                                           int* act, float (*fm)[8],
                                           int wid, int lane, int tid, int m7) {
    unsigned long long um[8];
    #pragma unroll
    for (int q = 0; q < 8; ++q) {
        unsigned long long u = zm7[0][q];
        #pragma unroll
        for (int s = 1; s < SPIKE_STEPS; ++s) u |= zm7[s][q];
        um[q] = u;
    }
    int pre = 0, total = 0;
    #pragma unroll
    for (int q = 0; q < 8; ++q) {
        int p = __popcll(um[q]);
        total += p;
        if (q < wid) pre += p;
    }
    if (m7 != 0) {
        int rank = pre + __popcll(um[wid] & ((1ull << lane) - 1ull));
        act[rank] = tid;
        #pragma unroll
        for (int s = 0; s < SPIKE_STEPS; ++s)
            fm[rank][s] = ((m7 >> s) & 1) ? 1.0f : 0.0f;
        fm[rank][7] = 0.f;
    }
    int npad = (total + 15) & ~15;
    if (tid < npad - total) {
        act[total + tid] = HIDDEN;   // zero-row pad
        #pragma unroll
        for (int s = 0; s < 8; ++s) fm[total + tid][s] = 0.f;
    }
    return npad;
}

// Two-stage pipeline: even blocks = producer (layer0+layer1), odd = consumer
// (layer2+output). Handoff granularity is now ONE SEQ STEP (7 masks at once):
// 7x fewer spins/ctr bumps, 4 barriers per seq step instead of ~21.
__launch_bounds__(512, 1)
__global__ void snn_pipe_kernel(const float* __restrict__ x,     // [256,128,96]
                                const float* __restrict__ Wout,  // [2,512]
                                const float* __restrict__ betas, // [3]
                                const float* __restrict__ thrs,  // [3]
                                const float* __restrict__ W0T,   // [96,512]
                                const float* __restrict__ W1T,   // [513,512]
                                const float* __restrict__ W2T,   // [513,512]
                                unsigned long long* __restrict__ zbuf,
                                int* __restrict__ ctr,
                                float* __restrict__ out)         // [256,128,2]
{
    const int b    = blockIdx.x >> 1;
    const int role = blockIdx.x & 1;
    const int tid  = threadIdx.x;
    const int lane = tid & 63;
    const int wid  = tid >> 6;

    __shared__ float xs[IN_DIM];
    __shared__ unsigned long long zm7[SPIKE_STEPS][8];
    __shared__ int act[HIDDEN];
    __shared__ float fm[HIDDEN][8];     // 16 KB: per-union-row step masks
    __shared__ float red[16];

    if (role == 0) {
        // ---------------- producer: layer0 + layer1 ----------------
        const float beta0 = betas[0], beta1 = betas[1];
        const float thr0  = thrs[0],  thr1  = thrs[1];
        float mem0 = 0.f, mem1 = 0.f;
        unsigned long long* zb = zbuf + (size_t)b * SEQ_LEN * 56;

        for (int i = 0; i < SEQ_LEN; ++i) {
            if (tid < IN_DIM) xs[tid] = x[(i * BATCH + b) * IN_DIM + tid];
            __syncthreads();                                        // B1

            float cur0 = 0.f;
            #pragma unroll 8
            for (int k = 0; k < IN_DIM; ++k)
                cur0 = __fmaf_rn(xs[k], W0T[k * HIDDEN + tid], cur0);

            // layer-0 recurrence is autonomous within the seq step:
            // compute all 7 z0 masks upfront.
            int m7 = 0;
            #pragma unroll
            for (int s = 0; s < SPIKE_STEPS; ++s) {
                bool reset0 = (mem0 - thr0) > 0.f;
                mem0 = reset0 ? 0.f : __fadd_rn(__fmul_rn(beta0, mem0), cur0);
                bool z0 = (mem0 - thr0) > 0.f;
                m7 |= (int)z0 << s;
                unsigned long long bal = __ballot(z0);
                if (lane == 0) zm7[s][wid] = bal;
            }
            __syncthreads();                                        // B2

            int npad = build_union(zm7, act, fm, wid, lane, tid, m7);
            __syncthreads();                                        // B3

            float acc[SPIKE_STEPS] = {0.f, 0.f, 0.f, 0.f, 0.f, 0.f, 0.f};
            row_sum7(W1T, act, fm, npad, tid, acc);

            // layer-1 recurrence over the 7 steps, emit z1 masks
            #pragma unroll
            for (int s = 0; s < SPIKE_STEPS; ++s) {
                bool reset1 = (mem1 - thr1) > 0.f;
                mem1 = reset1 ? 0.f : __fadd_rn(__fmul_rn(beta1, mem1), acc[s]);
                bool z1 = (mem1 - thr1) > 0.f;
                unsigned long long bal1 = __ballot(z1);
                if (lane == 0)
                    __hip_atomic_store(&zb[(size_t)i * 56 + s * 8 + wid], bal1,
                                       __ATOMIC_RELAXED, __HIP_MEMORY_SCOPE_AGENT);
            }
            __syncthreads();   // B4: all waves' mask stores drained (vmcnt 0)
            if (tid == 0)
                __hip_atomic_store(&ctr[b], i + 1,
                                   __ATOMIC_RELAXED, __HIP_MEMORY_SCOPE_AGENT);
        }
    } else {
        // ---------------- consumer: layer2 + output ----------------
        const float beta2 = betas[2];
        const float thr2  = thrs[2];
        const float wo0 = Wout[tid];
        const float wo1 = Wout[HIDDEN + tid];
        float mem2 = 0.f;
        // Deferred output reduction (R1): per-thread integrator a, prefix
        // accumulator w; one cross-thread reduction per seq step.
        float a0 = 0.f, a1 = 0.f;
        const unsigned long long* zb = zbuf + (size_t)b * SEQ_LEN * 56;

        for (int i = 0; i < SEQ_LEN; ++i) {
            if (tid == 0) {
                while (__hip_atomic_load(&ctr[b], __ATOMIC_RELAXED,
                                         __HIP_MEMORY_SCOPE_AGENT) < i + 1)
                    __builtin_amdgcn_s_sleep(1);
            }
            __syncthreads();                                        // B1

            if (tid < 56)
                ((unsigned long long*)zm7)[tid] =
                    __hip_atomic_load(&zb[(size_t)i * 56 + tid],
                                      __ATOMIC_RELAXED, __HIP_MEMORY_SCOPE_AGENT);
            __syncthreads();                                        // B2

            int m7 = 0;
            #pragma unroll
            for (int s = 0; s < SPIKE_STEPS; ++s)
                m7 |= (int)((zm7[s][wid] >> lane) & 1ull) << s;

            int npad = build_union(zm7, act, fm, wid, lane, tid, m7);
            __syncthreads();                                        // B3

            float acc[SPIKE_STEPS] = {0.f, 0.f, 0.f, 0.f, 0.f, 0.f, 0.f};
            row_sum7(W2T, act, fm, npad, tid, acc);

            float w0 = 0.f, w1 = 0.f;
            #pragma unroll
            for (int s = 0; s < SPIKE_STEPS; ++s) {
                bool reset2 = (mem2 - thr2) > 0.f;
                mem2 = reset2 ? 0.f : __fadd_rn(__fmul_rn(beta2, mem2), acc[s]);
                bool z2 = (mem2 - thr2) > 0.f;
                a0 += z2 ? wo0 : 0.f;
                a1 += z2 ? wo1 : 0.f;
                w0 += a0;
                w1 += a1;
            }

            // one cross-thread reduction per seq step
            float c0 = w0, c1 = w1;
            #pragma unroll
            for (int off = 32; off > 0; off >>= 1) {
                c0 += __shfl_down(c0, off);
                c1 += __shfl_down(c1, off);
            }
            if (lane == 0) { red[wid * 2] = c0; red[wid * 2 + 1] = c1; }
            __syncthreads();                                        // B4
            if (tid == 0) {
                float r0 = 0.f, r1 = 0.f;
                #pragma unroll
                for (int q = 0; q < 8; ++q) { r0 += red[q * 2]; r1 += red[q * 2 + 1]; }
                out[(i * BATCH + b) * OUT_DIM + 0] = r0 / 7.0f;
                out[(i * BATCH + b) * OUT_DIM + 1] = r1 / 7.0f;
            }
        }
    }
}

extern "C" void kernel_launch(void* const* d_in, const int* in_sizes, int n_in,
                              void* d_out, int out_size, void* d_ws, size_t ws_size,
                              hipStream_t stream) {
    const float* x     = (const float*)d_in[0];
    const float* W0    = (const float*)d_in[1];
    const float* W1    = (const float*)d_in[2];
    const float* W2    = (const float*)d_in[3];
    const float* Wout  = (const float*)d_in[4];
    const float* betas = (const float*)d_in[5];
    const float* thrs  = (const float*)d_in[6];
    float* out = (float*)d_out;

    float* ws  = (float*)d_ws;
    float* W0T = ws + W0T_OFF;
    float* W1T = ws + W1T_OFF;
    float* W2T = ws + W2T_OFF;
    int* ctr = (int*)((char*)d_ws + CTR_BYTE_OFF);
    unsigned long long* zbuf = (unsigned long long*)((char*)d_ws + ZBUF_BYTE_OFF);

    {
        int n = HIDDEN * IN_DIM;
        transpose_kernel<<<(n + 255) / 256, 256, 0, stream>>>(W0, W0T, HIDDEN, IN_DIM);
    }
    {
        int n = HIDDEN * HIDDEN;
        transpose_kernel<<<(n + 255) / 256, 256, 0, stream>>>(W1, W1T, HIDDEN, HIDDEN);
        transpose_kernel<<<(n + 255) / 256, 256, 0, stream>>>(W2, W2T, HIDDEN, HIDDEN);
    }

    // zero the pad row (index 512) of W1T/W2T, and the progress counters
    hipMemsetAsync(W1T + (size_t)HIDDEN * HIDDEN, 0, HIDDEN * sizeof(float), stream);
    hipMemsetAsync(W2T + (size_t)HIDDEN * HIDDEN, 0, HIDDEN * sizeof(float), stream);
    hipMemsetAsync((char*)d_ws + CTR_BYTE_OFF, 0, 1024, stream);

    snn_pipe_kernel<<<2 * BATCH, HIDDEN, 0, stream>>>(
        x, Wout, betas, thrs, W0T, W1T, W2T, zbuf, ctr, out);
}